// Round 7
// baseline (164.653 us; speedup 1.0000x reference)
//
#include <hip/hip_runtime.h>
#include <hip/hip_bf16.h>

#define GENES 20000
#define TFS   1500
#define BATCH 128
#define NR    8            // gene ranges (1 per XCD)
#define GPR   2500         // genes per range
#define NBINS (NR * TFS)   // 12000
#define NBS   256          // sort partitions (hist/place blocks)
#define NTRANS 2500        // 625 x 4 transpose tiles

__device__ __forceinline__ unsigned short f32_to_bf16_rn(float f) {
    unsigned int u = __float_as_uint(f);
    u += 0x7fffu + ((u >> 16) & 1u);
    return (unsigned short)(u >> 16);
}

// ---------------- K1: fused zero-out || transpose(x->bf16 xT) || per-block histogram ----------------
__global__ __launch_bounds__(256) void prep_k(const float* __restrict__ x,
                                              const int* __restrict__ gi,
                                              const int* __restrict__ ti,
                                              int E, int chunk,
                                              unsigned short* __restrict__ blkhist,
                                              unsigned short* __restrict__ xT,
                                              float* __restrict__ out, int nzero4) {
    __shared__ int sh[NBINS];              // 48 KB; transpose aliases first 4.3 KB
    int blk = blockIdx.x, tid = threadIdx.x;
    if (blk < NBS) {
        // ---- histogram role ----
        for (int i = tid; i < NBINS; i += 256) sh[i] = 0;
        __syncthreads();
        int lo = blk * chunk;
        int hi = min(lo + chunk, E);
        #pragma unroll 4
        for (int e = lo + tid; e < hi; e += 256) {
            int bin = (gi[e] / GPR) * TFS + ti[e];
            atomicAdd(&sh[bin], 1);        // LDS-scope ds_add
        }
        __syncthreads();
        for (int i = tid; i < NBINS; i += 256)
            blkhist[(size_t)blk * NBINS + i] = (unsigned short)sh[i];  // counts <= chunk < 65536
    } else if (blk < NBS + NTRANS) {
        // ---- transpose role: 32x32 tile ----
        float* tile = (float*)sh;          // [32][33]
        int tb = blk - NBS;
        int gt = tb % 625, bt = tb / 625;
        int g0 = gt * 32, b0 = bt * 32;
        int tx = tid & 31, r0 = tid >> 5;  // 8 rows per pass, 4 passes
        #pragma unroll
        for (int it = 0; it < 4; ++it) {
            int ty = r0 + it * 8;
            tile[ty * 33 + tx] = x[(size_t)(b0 + ty) * GENES + (g0 + tx)];
        }
        __syncthreads();
        #pragma unroll
        for (int it = 0; it < 4; ++it) {
            int ty = r0 + it * 8;
            xT[(size_t)(g0 + ty) * BATCH + (b0 + tx)] = f32_to_bf16_rn(tile[tx * 33 + ty]);
        }
    } else {
        // ---- zero-out role (out accumulated atomically later) ----
        int idx4 = (blk - (NBS + NTRANS)) * 256 + tid;
        if (idx4 < nzero4) {
            float4 z; z.x = 0.f; z.y = 0.f; z.z = 0.f; z.w = 0.f;
            ((float4*)out)[idx4] = z;
        }
    }
}

// ---------------- K2: per-bin column prefix over NBS blocks (in place, ushort) + totals ----------------
__global__ __launch_bounds__(256) void mid_k(unsigned short* __restrict__ blkhist,
                                             int* __restrict__ totals) {
    int bin = blockIdx.x * 256 + threadIdx.x;
    if (bin >= NBINS) return;
    int run = 0;
    #pragma unroll 8
    for (int b = 0; b < NBS; ++b) {
        size_t idx = (size_t)b * NBINS + bin;
        int v = blkhist[idx];
        blkhist[idx] = (unsigned short)run;   // local exclusive prefix (< chunk, fits ushort)
        run += v;
    }
    totals[bin] = run;
}

// ---------------- K3: redundant LDS scan of totals + place edges at exact sorted slots ----------------
__global__ __launch_bounds__(512) void place_k(const int* __restrict__ gi,
                                               const int* __restrict__ ti,
                                               const float* __restrict__ w,
                                               int E, int chunk,
                                               const unsigned short* __restrict__ blkoff,
                                               const int* __restrict__ totals,
                                               int* __restrict__ bin_start,
                                               unsigned long long* __restrict__ binned) {
    __shared__ int cur[NBINS];
    __shared__ int wsum[8];
    int blk = blockIdx.x, tid = threadIdx.x;

    // exclusive scan of 12000 totals, contiguous 24-bin segments per thread
    const int SEG = 24;                    // 512*24 = 12288 >= NBINS
    int base = tid * SEG;
    int loc[SEG];
    int s = 0;
    #pragma unroll
    for (int i = 0; i < SEG; ++i) {
        int bi = base + i;
        int v = (bi < NBINS) ? totals[bi] : 0;
        loc[i] = s;
        s += v;
    }
    int lane = tid & 63, wid = tid >> 6;
    int inc = s;
    #pragma unroll
    for (int d = 1; d < 64; d <<= 1) {
        int u = __shfl_up(inc, d, 64);
        if (lane >= d) inc += u;
    }
    if (lane == 63) wsum[wid] = inc;
    __syncthreads();
    if (tid == 0) {
        int r = 0;
        #pragma unroll
        for (int i = 0; i < 8; ++i) { int v = wsum[i]; wsum[i] = r; r += v; }
    }
    __syncthreads();
    int excl = wsum[wid] + (inc - s);
    #pragma unroll
    for (int i = 0; i < SEG; ++i) {
        int bi = base + i;
        if (bi < NBINS) cur[bi] = excl + loc[i];
    }
    __syncthreads();
    // fold in this block's blkoff; block 0 (blkoff==0) publishes bin_start for compute
    for (int i = tid; i < NBINS; i += 512) {
        int bs = cur[i];
        if (blk == 0) bin_start[i] = bs;
        cur[i] = bs + (int)blkoff[(size_t)blk * NBINS + i];
    }
    if (blk == 0 && tid == 0) bin_start[NBINS] = E;
    __syncthreads();

    int lo = blk * chunk;
    int hi = min(lo + chunk, E);
    #pragma unroll 4
    for (int e = lo + tid; e < hi; e += 512) {
        int g = gi[e];
        int bin = (g / GPR) * TFS + ti[e];
        int pos = atomicAdd(&cur[bin], 1);     // ds_add_rtn, LDS-scope
        binned[pos] = ((unsigned long long)__float_as_uint(w[e]) << 32) | (unsigned int)g;
    }
}

// ---------------- K4: one bin per 64-thread block; thread owns 2 batch cols; atomics into out ----------------
__global__ __launch_bounds__(64) void compute_k(
        const unsigned long long* __restrict__ binned,
        const int* __restrict__ bin_start,
        const unsigned short* __restrict__ xT,
        float* __restrict__ out) {
    int gid = blockIdx.x;
    int r  = gid & 7;                      // XCD-pinned range under round-robin
    int tf = gid >> 3;
    int bin = r * TFS + tf;
    int s = bin_start[bin];
    int e = bin_start[bin + 1];
    if (s >= e) return;
    int tid = threadIdx.x;
    float acc0 = 0.0f, acc1 = 0.0f;
    __shared__ unsigned long long lds[192];
    for (int base = s; base < e; base += 192) {
        int cnt = min(192, e - base);
        __syncthreads();
        for (int i = tid; i < cnt; i += 64) lds[i] = binned[base + i];
        __syncthreads();
        #pragma unroll 8
        for (int i = 0; i < cnt; ++i) {
            unsigned long long p = lds[i];         // uniform address -> LDS broadcast
            int g = (int)(unsigned int)(p & 0xffffffffu);
            float wv = __uint_as_float((unsigned int)(p >> 32));
            unsigned int xx = *(const unsigned int*)&xT[(size_t)g * BATCH + 2 * tid];
            acc0 += wv * __uint_as_float(xx << 16);
            acc1 += wv * __uint_as_float(xx & 0xffff0000u);
        }
    }
    atomicAdd(&out[(size_t)(2 * tid)     * TFS + tf], acc0);
    atomicAdd(&out[(size_t)(2 * tid + 1) * TFS + tf], acc1);
}

// ---------------- fallback (ws too small): direct atomics ----------------
__global__ void zero_f32(float* __restrict__ p, int n) {
    int i = blockIdx.x * 256 + threadIdx.x;
    if (i < n) p[i] = 0.0f;
}

__global__ void fallback_kernel(const float* __restrict__ x, const float* __restrict__ w,
                                const int* __restrict__ gi, const int* __restrict__ ti,
                                int E, float* __restrict__ out) {
    long long idx = (long long)blockIdx.x * blockDim.x + threadIdx.x;
    long long total = (long long)E * 64;
    if (idx >= total) return;
    int e = (int)(idx >> 6);
    int b2 = (int)(idx & 63);
    int g = gi[e], t = ti[e];
    float wv = w[e];
    int b0 = b2 * 2;
    atomicAdd(&out[(size_t)b0 * TFS + t], wv * x[(size_t)b0 * GENES + g]);
    atomicAdd(&out[(size_t)(b0 + 1) * TFS + t], wv * x[(size_t)(b0 + 1) * GENES + g]);
}

extern "C" void kernel_launch(void* const* d_in, const int* in_sizes, int n_in,
                              void* d_out, int out_size, void* d_ws, size_t ws_size,
                              hipStream_t stream) {
    const float* x  = (const float*)d_in[0];
    const float* w  = (const float*)d_in[1];
    const int*   gi = (const int*)d_in[2];
    const int*   ti = (const int*)d_in[3];
    float* out = (float*)d_out;
    int E = in_sizes[1];
    int chunk = (E + NBS - 1) / NBS;

    size_t xT_bytes       = (size_t)GENES * BATCH * 2;               //  5,120,000
    size_t binned_bytes   = ((size_t)E * 8 + 15) & ~(size_t)15;      //  8,000,000
    size_t blkhist_bytes  = (size_t)NBS * NBINS * 2;                 //  6,144,000
    size_t binstart_bytes = ((size_t)(NBINS + 1) * 4 + 15) & ~(size_t)15;
    size_t totals_bytes   = (size_t)NBINS * 4;
    size_t need = xT_bytes + binned_bytes + blkhist_bytes + binstart_bytes + totals_bytes;

    if (ws_size < need) {
        zero_f32<<<(out_size + 255) / 256, 256, 0, stream>>>(out, out_size);
        long long total = (long long)E * 64;
        int blocks = (int)((total + 255) / 256);
        fallback_kernel<<<blocks, 256, 0, stream>>>(x, w, gi, ti, E, out);
        return;
    }

    char* ws = (char*)d_ws;
    unsigned short*     xT        = (unsigned short*)ws;
    unsigned long long* binned    = (unsigned long long*)(ws + xT_bytes);
    unsigned short*     blkhist   = (unsigned short*)(ws + xT_bytes + binned_bytes);
    int*                bin_start = (int*)(ws + xT_bytes + binned_bytes + blkhist_bytes);
    int*                totals    = (int*)(ws + xT_bytes + binned_bytes + blkhist_bytes + binstart_bytes);

    int nzero4 = out_size / 4;                               // 48000 float4s (out_size = 192000)
    int nzero_blocks = (nzero4 + 255) / 256;                 // 188
    int prep_grid = NBS + NTRANS + nzero_blocks;             // 2944

    prep_k   <<<prep_grid, 256, 0, stream>>>(x, gi, ti, E, chunk, blkhist, xT, out, nzero4);
    mid_k    <<<(NBINS + 255) / 256, 256, 0, stream>>>(blkhist, totals);
    place_k  <<<NBS, 512, 0, stream>>>(gi, ti, w, E, chunk, blkhist, totals, bin_start, binned);
    compute_k<<<NBINS, 64, 0, stream>>>(binned, bin_start, xT, out);
}

// Round 8
// 77.400 us; speedup vs baseline: 2.1273x; 2.1273x over previous
//
#include <hip/hip_runtime.h>
#include <hip/hip_bf16.h>

#define GENES 20000
#define TFS   1500
#define BATCH 128
#define NR    8            // gene ranges (1 per XCD)
#define GPR   2500         // genes per range
#define NBINS (NR * TFS)   // 12000
#define NBS   256          // sort partitions (hist/place blocks)
#define NTRANS 2500        // 625 x 4 transpose tiles

__device__ __forceinline__ unsigned short f32_to_bf16_rn(float f) {
    unsigned int u = __float_as_uint(f);
    u += 0x7fffu + ((u >> 16) & 1u);
    return (unsigned short)(u >> 16);
}

// ---------------- K1: fused transpose(x->bf16 xT) || per-block histogram ----------------
__global__ __launch_bounds__(256) void prep_k(const float* __restrict__ x,
                                              const int* __restrict__ gi,
                                              const int* __restrict__ ti,
                                              int E, int chunk,
                                              unsigned short* __restrict__ blkhist,
                                              unsigned short* __restrict__ xT) {
    __shared__ int sh[NBINS];              // 48 KB; transpose aliases first 4.3 KB
    int blk = blockIdx.x, tid = threadIdx.x;
    if (blk < NBS) {
        // ---- histogram role ----
        for (int i = tid; i < NBINS; i += 256) sh[i] = 0;
        __syncthreads();
        int lo = blk * chunk;
        int hi = min(lo + chunk, E);
        #pragma unroll 4
        for (int e = lo + tid; e < hi; e += 256) {
            int bin = (gi[e] / GPR) * TFS + ti[e];
            atomicAdd(&sh[bin], 1);        // LDS-scope ds_add
        }
        __syncthreads();
        for (int i = tid; i < NBINS; i += 256)
            blkhist[(size_t)blk * NBINS + i] = (unsigned short)sh[i];  // counts <= chunk < 65536
    } else {
        // ---- transpose role: 32x32 tile ----
        float* tile = (float*)sh;          // [32][33]
        int tb = blk - NBS;
        int gt = tb % 625, bt = tb / 625;
        int g0 = gt * 32, b0 = bt * 32;
        int tx = tid & 31, r0 = tid >> 5;  // 8 rows per pass, 4 passes
        #pragma unroll
        for (int it = 0; it < 4; ++it) {
            int ty = r0 + it * 8;
            tile[ty * 33 + tx] = x[(size_t)(b0 + ty) * GENES + (g0 + tx)];
        }
        __syncthreads();
        #pragma unroll
        for (int it = 0; it < 4; ++it) {
            int ty = r0 + it * 8;
            xT[(size_t)(g0 + ty) * BATCH + (b0 + tx)] = f32_to_bf16_rn(tile[tx * 33 + ty]);
        }
    }
}

// ---------------- K2: per-bin column prefix over NBS blocks (in place, ushort) + totals ----------------
__global__ __launch_bounds__(256) void mid_k(unsigned short* __restrict__ blkhist,
                                             int* __restrict__ totals) {
    int bin = blockIdx.x * 256 + threadIdx.x;
    if (bin >= NBINS) return;
    int run = 0;
    #pragma unroll 8
    for (int b = 0; b < NBS; ++b) {
        size_t idx = (size_t)b * NBINS + bin;
        int v = blkhist[idx];
        blkhist[idx] = (unsigned short)run;   // local exclusive prefix (< chunk, fits ushort)
        run += v;
    }
    totals[bin] = run;
}

// ---------------- K3: redundant LDS scan of totals + place edges at exact sorted slots ----------------
__global__ __launch_bounds__(512) void place_k(const int* __restrict__ gi,
                                               const int* __restrict__ ti,
                                               const float* __restrict__ w,
                                               int E, int chunk,
                                               const unsigned short* __restrict__ blkoff,
                                               const int* __restrict__ totals,
                                               int* __restrict__ bin_start,
                                               unsigned long long* __restrict__ binned) {
    __shared__ int cur[NBINS];
    __shared__ int wsum[8];
    int blk = blockIdx.x, tid = threadIdx.x;

    // exclusive scan of 12000 totals, contiguous 24-bin segments per thread
    const int SEG = 24;                    // 512*24 = 12288 >= NBINS
    int base = tid * SEG;
    int loc[SEG];
    int s = 0;
    #pragma unroll
    for (int i = 0; i < SEG; ++i) {
        int bi = base + i;
        int v = (bi < NBINS) ? totals[bi] : 0;
        loc[i] = s;
        s += v;
    }
    int lane = tid & 63, wid = tid >> 6;
    int inc = s;
    #pragma unroll
    for (int d = 1; d < 64; d <<= 1) {
        int u = __shfl_up(inc, d, 64);
        if (lane >= d) inc += u;
    }
    if (lane == 63) wsum[wid] = inc;
    __syncthreads();
    if (tid == 0) {
        int r = 0;
        #pragma unroll
        for (int i = 0; i < 8; ++i) { int v = wsum[i]; wsum[i] = r; r += v; }
    }
    __syncthreads();
    int excl = wsum[wid] + (inc - s);
    #pragma unroll
    for (int i = 0; i < SEG; ++i) {
        int bi = base + i;
        if (bi < NBINS) cur[bi] = excl + loc[i];
    }
    __syncthreads();
    // fold in this block's blkoff; block 0 (blkoff==0) publishes bin_start for compute
    for (int i = tid; i < NBINS; i += 512) {
        int bs = cur[i];
        if (blk == 0) bin_start[i] = bs;
        cur[i] = bs + (int)blkoff[(size_t)blk * NBINS + i];
    }
    if (blk == 0 && tid == 0) bin_start[NBINS] = E;
    __syncthreads();

    int lo = blk * chunk;
    int hi = min(lo + chunk, E);
    #pragma unroll 4
    for (int e = lo + tid; e < hi; e += 512) {
        int g = gi[e];
        int bin = (g / GPR) * TFS + ti[e];
        int pos = atomicAdd(&cur[bin], 1);     // ds_add_rtn, LDS-scope
        binned[pos] = ((unsigned long long)__float_as_uint(w[e]) << 32) | (unsigned int)g;
    }
}

// ---------------- K4: one bin per 64-thread block; thread owns 2 batch cols; plain stores ----------------
__global__ __launch_bounds__(64) void compute_k(
        const unsigned long long* __restrict__ binned,
        const int* __restrict__ bin_start,
        const unsigned short* __restrict__ xT,
        float* __restrict__ out8) {
    int gid = blockIdx.x;
    int r  = gid & 7;                      // XCD-pinned range under round-robin
    int tf = gid >> 3;
    int bin = r * TFS + tf;
    int s = bin_start[bin];
    int e = bin_start[bin + 1];
    int tid = threadIdx.x;
    float acc0 = 0.0f, acc1 = 0.0f;
    __shared__ unsigned long long lds[192];
    for (int base = s; base < e; base += 192) {
        int cnt = min(192, e - base);
        __syncthreads();
        for (int i = tid; i < cnt; i += 64) lds[i] = binned[base + i];
        __syncthreads();
        #pragma unroll 8
        for (int i = 0; i < cnt; ++i) {
            unsigned long long p = lds[i];         // uniform address -> LDS broadcast
            int g = (int)(unsigned int)(p & 0xffffffffu);
            float wv = __uint_as_float((unsigned int)(p >> 32));
            unsigned int xx = *(const unsigned int*)&xT[(size_t)g * BATCH + 2 * tid];
            acc0 += wv * __uint_as_float(xx << 16);
            acc1 += wv * __uint_as_float(xx & 0xffff0000u);
        }
    }
    // ALWAYS store (even empty bins) -- out8 aliases poisoned blkhist memory.
    float2 st; st.x = acc0; st.y = acc1;
    *(float2*)&out8[((size_t)bin) * BATCH + 2 * tid] = st;
}

// ---------------- K5: transpose + reduce 8 partials: out[b][t] = sum_r out8[r][t][b] ----------------
__global__ void transpose_out8(const float* __restrict__ out8, float* __restrict__ out) {
    __shared__ float tile[32][33];
    int t0 = blockIdx.x * 32;
    int b0 = blockIdx.y * 32;
    int tx = threadIdx.x, ty = threadIdx.y;
    int t = t0 + ty;
    if (t < TFS) {
        float s = 0.0f;
        #pragma unroll
        for (int r = 0; r < NR; ++r)
            s += out8[((size_t)r * TFS + t) * BATCH + (b0 + tx)];
        tile[ty][tx] = s;
    }
    __syncthreads();
    if (t0 + tx < TFS)
        out[(size_t)(b0 + ty) * TFS + (t0 + tx)] = tile[tx][ty];
}

// ---------------- fallback (ws too small): direct atomics ----------------
__global__ void zero_f32(float* __restrict__ p, int n) {
    int i = blockIdx.x * 256 + threadIdx.x;
    if (i < n) p[i] = 0.0f;
}

__global__ void fallback_kernel(const float* __restrict__ x, const float* __restrict__ w,
                                const int* __restrict__ gi, const int* __restrict__ ti,
                                int E, float* __restrict__ out) {
    long long idx = (long long)blockIdx.x * blockDim.x + threadIdx.x;
    long long total = (long long)E * 64;
    if (idx >= total) return;
    int e = (int)(idx >> 6);
    int b2 = (int)(idx & 63);
    int g = gi[e], t = ti[e];
    float wv = w[e];
    int b0 = b2 * 2;
    atomicAdd(&out[(size_t)b0 * TFS + t], wv * x[(size_t)b0 * GENES + g]);
    atomicAdd(&out[(size_t)(b0 + 1) * TFS + t], wv * x[(size_t)(b0 + 1) * GENES + g]);
}

extern "C" void kernel_launch(void* const* d_in, const int* in_sizes, int n_in,
                              void* d_out, int out_size, void* d_ws, size_t ws_size,
                              hipStream_t stream) {
    const float* x  = (const float*)d_in[0];
    const float* w  = (const float*)d_in[1];
    const int*   gi = (const int*)d_in[2];
    const int*   ti = (const int*)d_in[3];
    float* out = (float*)d_out;
    int E = in_sizes[1];
    int chunk = (E + NBS - 1) / NBS;

    size_t xT_bytes       = (size_t)GENES * BATCH * 2;               //  5,120,000
    size_t binned_bytes   = ((size_t)E * 8 + 15) & ~(size_t)15;      //  8,000,000
    size_t blkhist_bytes  = (size_t)NBS * NBINS * 2;                 //  6,144,000
    size_t out8_bytes     = (size_t)NR * TFS * BATCH * 4;            //  6,144,000 (aliases blkhist)
    size_t big_bytes      = blkhist_bytes > out8_bytes ? blkhist_bytes : out8_bytes;
    size_t binstart_bytes = ((size_t)(NBINS + 1) * 4 + 15) & ~(size_t)15;
    size_t totals_bytes   = (size_t)NBINS * 4;
    size_t need = xT_bytes + binned_bytes + big_bytes + binstart_bytes + totals_bytes;

    if (ws_size < need) {
        zero_f32<<<(out_size + 255) / 256, 256, 0, stream>>>(out, out_size);
        long long total = (long long)E * 64;
        int blocks = (int)((total + 255) / 256);
        fallback_kernel<<<blocks, 256, 0, stream>>>(x, w, gi, ti, E, out);
        return;
    }

    char* ws = (char*)d_ws;
    unsigned short*     xT        = (unsigned short*)ws;
    unsigned long long* binned    = (unsigned long long*)(ws + xT_bytes);
    unsigned short*     blkhist   = (unsigned short*)(ws + xT_bytes + binned_bytes);
    float*              out8      = (float*)blkhist;   // alias: blkhist dead after place_k
    int*                bin_start = (int*)(ws + xT_bytes + binned_bytes + big_bytes);
    int*                totals    = (int*)(ws + xT_bytes + binned_bytes + big_bytes + binstart_bytes);

    int prep_grid = NBS + NTRANS;          // 2756

    prep_k   <<<prep_grid, 256, 0, stream>>>(x, gi, ti, E, chunk, blkhist, xT);
    mid_k    <<<(NBINS + 255) / 256, 256, 0, stream>>>(blkhist, totals);
    place_k  <<<NBS, 512, 0, stream>>>(gi, ti, w, E, chunk, blkhist, totals, bin_start, binned);
    compute_k<<<NBINS, 64, 0, stream>>>(binned, bin_start, xT, out8);
    transpose_out8<<<dim3((TFS + 31) / 32, BATCH / 32), dim3(32, 32), 0, stream>>>(out8, out);
}

// Round 9
// 73.147 us; speedup vs baseline: 2.2510x; 1.0581x over previous
//
#include <hip/hip_runtime.h>
#include <hip/hip_bf16.h>

#define GENES 20000
#define TFS   1500
#define BATCH 128
#define NR    8            // gene ranges (1 per XCD)
#define GPR   2500         // genes per range
#define NBINS (NR * TFS)   // 12000
#define NBS   256          // sort partitions (hist/place blocks)
#define NTRANS 2500        // 625 x 4 transpose tiles

__device__ __forceinline__ unsigned short f32_to_bf16_rn(float f) {
    unsigned int u = __float_as_uint(f);
    u += 0x7fffu + ((u >> 16) & 1u);
    return (unsigned short)(u >> 16);
}

// ---------------- K1: fused transpose(x->bf16 xT) || per-block histogram ----------------
__global__ __launch_bounds__(512) void prep_k(const float* __restrict__ x,
                                              const int* __restrict__ gi,
                                              const int* __restrict__ ti,
                                              int E, int chunk,
                                              unsigned short* __restrict__ blkhist,
                                              unsigned short* __restrict__ xT) {
    __shared__ int sh[NBINS];              // 48 KB; transpose aliases first 4.3 KB
    int blk = blockIdx.x, tid = threadIdx.x;
    if (blk < NBS) {
        // ---- histogram role: int4 edge loads (4 edges/iter) ----
        for (int i = tid; i < NBINS; i += 512) sh[i] = 0;
        __syncthreads();
        int lo = blk * chunk;
        int hi = min(lo + chunk, E);
        int n  = hi - lo;
        if (n > 0) {
            int n4 = n >> 2;
            const int4* gi4 = (const int4*)(gi + lo);
            const int4* ti4 = (const int4*)(ti + lo);
            for (int j = tid; j < n4; j += 512) {
                int4 g4 = gi4[j];
                int4 t4 = ti4[j];
                atomicAdd(&sh[(g4.x / GPR) * TFS + t4.x], 1);
                atomicAdd(&sh[(g4.y / GPR) * TFS + t4.y], 1);
                atomicAdd(&sh[(g4.z / GPR) * TFS + t4.z], 1);
                atomicAdd(&sh[(g4.w / GPR) * TFS + t4.w], 1);
            }
            for (int e = lo + (n4 << 2) + tid; e < hi; e += 512)  // tail (E%4 safety)
                atomicAdd(&sh[(gi[e] / GPR) * TFS + ti[e]], 1);
        }
        __syncthreads();
        for (int i = tid; i < NBINS; i += 512)
            blkhist[(size_t)blk * NBINS + i] = (unsigned short)sh[i];  // counts <= chunk
    } else {
        // ---- transpose role: 32x32 tile, 512 threads = 2 passes of 16 rows ----
        float* tile = (float*)sh;          // [32][33]
        int tb = blk - NBS;
        int gt = tb % 625, bt = tb / 625;
        int g0 = gt * 32, b0 = bt * 32;
        int tx = tid & 31, r0 = tid >> 5;  // r0 in 0..15
        #pragma unroll
        for (int it = 0; it < 2; ++it) {
            int ty = r0 + it * 16;
            tile[ty * 33 + tx] = x[(size_t)(b0 + ty) * GENES + (g0 + tx)];
        }
        __syncthreads();
        #pragma unroll
        for (int it = 0; it < 2; ++it) {
            int ty = r0 + it * 16;
            xT[(size_t)(g0 + ty) * BATCH + (b0 + tx)] = f32_to_bf16_rn(tile[tx * 33 + ty]);
        }
    }
}

// ---------------- K2: per-bin column prefix over NBS blocks (in place, ushort) + totals ----------------
__global__ __launch_bounds__(256) void mid_k(unsigned short* __restrict__ blkhist,
                                             int* __restrict__ totals) {
    int bin = blockIdx.x * 256 + threadIdx.x;
    if (bin >= NBINS) return;
    int run = 0;
    #pragma unroll 8
    for (int b = 0; b < NBS; ++b) {
        size_t idx = (size_t)b * NBINS + bin;
        int v = blkhist[idx];
        blkhist[idx] = (unsigned short)run;   // local exclusive prefix (< chunk, fits ushort)
        run += v;
    }
    totals[bin] = run;
}

// ---------------- K3: redundant LDS scan of totals + vectorized place ----------------
__global__ __launch_bounds__(512) void place_k(const int* __restrict__ gi,
                                               const int* __restrict__ ti,
                                               const float* __restrict__ w,
                                               int E, int chunk,
                                               const unsigned short* __restrict__ blkoff,
                                               const int* __restrict__ totals,
                                               int* __restrict__ bin_start,
                                               unsigned long long* __restrict__ binned) {
    __shared__ int cur[NBINS];
    __shared__ int wsum[8];
    int blk = blockIdx.x, tid = threadIdx.x;

    // exclusive scan of 12000 totals, contiguous 24-bin segments per thread
    const int SEG = 24;                    // 512*24 = 12288 >= NBINS
    int base = tid * SEG;
    int loc[SEG];
    int s = 0;
    #pragma unroll
    for (int i = 0; i < SEG; ++i) {
        int bi = base + i;
        int v = (bi < NBINS) ? totals[bi] : 0;
        loc[i] = s;
        s += v;
    }
    int lane = tid & 63, wid = tid >> 6;
    int inc = s;
    #pragma unroll
    for (int d = 1; d < 64; d <<= 1) {
        int u = __shfl_up(inc, d, 64);
        if (lane >= d) inc += u;
    }
    if (lane == 63) wsum[wid] = inc;
    __syncthreads();
    if (tid == 0) {
        int r = 0;
        #pragma unroll
        for (int i = 0; i < 8; ++i) { int v = wsum[i]; wsum[i] = r; r += v; }
    }
    __syncthreads();
    int excl = wsum[wid] + (inc - s);
    #pragma unroll
    for (int i = 0; i < SEG; ++i) {
        int bi = base + i;
        if (bi < NBINS) cur[bi] = excl + loc[i];
    }
    __syncthreads();
    // fold in this block's blkoff; block 0 (blkoff==0) publishes bin_start for compute
    for (int i = tid; i < NBINS; i += 512) {
        int bs = cur[i];
        if (blk == 0) bin_start[i] = bs;
        cur[i] = bs + (int)blkoff[(size_t)blk * NBINS + i];
    }
    if (blk == 0 && tid == 0) bin_start[NBINS] = E;
    __syncthreads();

    int lo = blk * chunk;
    int hi = min(lo + chunk, E);
    int n  = hi - lo;
    if (n <= 0) return;
    int n4 = n >> 2;
    const int4*   gi4 = (const int4*)(gi + lo);
    const int4*   ti4 = (const int4*)(ti + lo);
    const float4* w4  = (const float4*)(w + lo);
    for (int j = tid; j < n4; j += 512) {
        int4   g4 = gi4[j];
        int4   t4 = ti4[j];
        float4 ww = w4[j];
        int b0 = (g4.x / GPR) * TFS + t4.x;
        int b1 = (g4.y / GPR) * TFS + t4.y;
        int b2 = (g4.z / GPR) * TFS + t4.z;
        int b3 = (g4.w / GPR) * TFS + t4.w;
        int p0 = atomicAdd(&cur[b0], 1);   // ds_add_rtn, LDS-scope, independent chains
        int p1 = atomicAdd(&cur[b1], 1);
        int p2 = atomicAdd(&cur[b2], 1);
        int p3 = atomicAdd(&cur[b3], 1);
        binned[p0] = ((unsigned long long)__float_as_uint(ww.x) << 32) | (unsigned int)g4.x;
        binned[p1] = ((unsigned long long)__float_as_uint(ww.y) << 32) | (unsigned int)g4.y;
        binned[p2] = ((unsigned long long)__float_as_uint(ww.z) << 32) | (unsigned int)g4.z;
        binned[p3] = ((unsigned long long)__float_as_uint(ww.w) << 32) | (unsigned int)g4.w;
    }
    for (int e = lo + (n4 << 2) + tid; e < hi; e += 512) {  // tail (E%4 safety)
        int g = gi[e];
        int bin = (g / GPR) * TFS + ti[e];
        int pos = atomicAdd(&cur[bin], 1);
        binned[pos] = ((unsigned long long)__float_as_uint(w[e]) << 32) | (unsigned int)g;
    }
}

// ---------------- K4: one bin per 64-thread block; thread owns 2 batch cols; plain stores ----------------
__global__ __launch_bounds__(64) void compute_k(
        const unsigned long long* __restrict__ binned,
        const int* __restrict__ bin_start,
        const unsigned short* __restrict__ xT,
        float* __restrict__ out8) {
    int gid = blockIdx.x;
    int r  = gid & 7;                      // XCD-pinned range under round-robin
    int tf = gid >> 3;
    int bin = r * TFS + tf;
    int s = bin_start[bin];
    int e = bin_start[bin + 1];
    int tid = threadIdx.x;
    float acc0 = 0.0f, acc1 = 0.0f;
    __shared__ unsigned long long lds[192];
    for (int base = s; base < e; base += 192) {
        int cnt = min(192, e - base);
        __syncthreads();
        for (int i = tid; i < cnt; i += 64) lds[i] = binned[base + i];
        __syncthreads();
        #pragma unroll 8
        for (int i = 0; i < cnt; ++i) {
            unsigned long long p = lds[i];         // uniform address -> LDS broadcast
            int g = (int)(unsigned int)(p & 0xffffffffu);
            float wv = __uint_as_float((unsigned int)(p >> 32));
            unsigned int xx = *(const unsigned int*)&xT[(size_t)g * BATCH + 2 * tid];
            acc0 += wv * __uint_as_float(xx << 16);
            acc1 += wv * __uint_as_float(xx & 0xffff0000u);
        }
    }
    // ALWAYS store (even empty bins) -- out8 aliases poisoned blkhist memory.
    float2 st; st.x = acc0; st.y = acc1;
    *(float2*)&out8[((size_t)bin) * BATCH + 2 * tid] = st;
}

// ---------------- K5: transpose + reduce 8 partials: out[b][t] = sum_r out8[r][t][b] ----------------
__global__ void transpose_out8(const float* __restrict__ out8, float* __restrict__ out) {
    __shared__ float tile[32][33];
    int t0 = blockIdx.x * 32;
    int b0 = blockIdx.y * 32;
    int tx = threadIdx.x, ty = threadIdx.y;
    int t = t0 + ty;
    if (t < TFS) {
        float s = 0.0f;
        #pragma unroll
        for (int r = 0; r < NR; ++r)
            s += out8[((size_t)r * TFS + t) * BATCH + (b0 + tx)];
        tile[ty][tx] = s;
    }
    __syncthreads();
    if (t0 + tx < TFS)
        out[(size_t)(b0 + ty) * TFS + (t0 + tx)] = tile[tx][ty];
}

// ---------------- fallback (ws too small): direct atomics ----------------
__global__ void zero_f32(float* __restrict__ p, int n) {
    int i = blockIdx.x * 256 + threadIdx.x;
    if (i < n) p[i] = 0.0f;
}

__global__ void fallback_kernel(const float* __restrict__ x, const float* __restrict__ w,
                                const int* __restrict__ gi, const int* __restrict__ ti,
                                int E, float* __restrict__ out) {
    long long idx = (long long)blockIdx.x * blockDim.x + threadIdx.x;
    long long total = (long long)E * 64;
    if (idx >= total) return;
    int e = (int)(idx >> 6);
    int b2 = (int)(idx & 63);
    int g = gi[e], t = ti[e];
    float wv = w[e];
    int b0 = b2 * 2;
    atomicAdd(&out[(size_t)b0 * TFS + t], wv * x[(size_t)b0 * GENES + g]);
    atomicAdd(&out[(size_t)(b0 + 1) * TFS + t], wv * x[(size_t)(b0 + 1) * GENES + g]);
}

extern "C" void kernel_launch(void* const* d_in, const int* in_sizes, int n_in,
                              void* d_out, int out_size, void* d_ws, size_t ws_size,
                              hipStream_t stream) {
    const float* x  = (const float*)d_in[0];
    const float* w  = (const float*)d_in[1];
    const int*   gi = (const int*)d_in[2];
    const int*   ti = (const int*)d_in[3];
    float* out = (float*)d_out;
    int E = in_sizes[1];
    int chunk = (((E + NBS - 1) / NBS) + 3) & ~3;   // multiple of 4 for int4 loads

    size_t xT_bytes       = (size_t)GENES * BATCH * 2;               //  5,120,000
    size_t binned_bytes   = ((size_t)E * 8 + 15) & ~(size_t)15;      //  8,000,000
    size_t blkhist_bytes  = (size_t)NBS * NBINS * 2;                 //  6,144,000
    size_t out8_bytes     = (size_t)NR * TFS * BATCH * 4;            //  6,144,000 (aliases blkhist)
    size_t big_bytes      = blkhist_bytes > out8_bytes ? blkhist_bytes : out8_bytes;
    size_t binstart_bytes = ((size_t)(NBINS + 1) * 4 + 15) & ~(size_t)15;
    size_t totals_bytes   = (size_t)NBINS * 4;
    size_t need = xT_bytes + binned_bytes + big_bytes + binstart_bytes + totals_bytes;

    if (ws_size < need) {
        zero_f32<<<(out_size + 255) / 256, 256, 0, stream>>>(out, out_size);
        long long total = (long long)E * 64;
        int blocks = (int)((total + 255) / 256);
        fallback_kernel<<<blocks, 256, 0, stream>>>(x, w, gi, ti, E, out);
        return;
    }

    char* ws = (char*)d_ws;
    unsigned short*     xT        = (unsigned short*)ws;
    unsigned long long* binned    = (unsigned long long*)(ws + xT_bytes);
    unsigned short*     blkhist   = (unsigned short*)(ws + xT_bytes + binned_bytes);
    float*              out8      = (float*)blkhist;   // alias: blkhist dead after place_k
    int*                bin_start = (int*)(ws + xT_bytes + binned_bytes + big_bytes);
    int*                totals    = (int*)(ws + xT_bytes + binned_bytes + big_bytes + binstart_bytes);

    int prep_grid = NBS + NTRANS;          // 2756

    prep_k   <<<prep_grid, 512, 0, stream>>>(x, gi, ti, E, chunk, blkhist, xT);
    mid_k    <<<(NBINS + 255) / 256, 256, 0, stream>>>(blkhist, totals);
    place_k  <<<NBS, 512, 0, stream>>>(gi, ti, w, E, chunk, blkhist, totals, bin_start, binned);
    compute_k<<<NBINS, 64, 0, stream>>>(binned, bin_start, xT, out8);
    transpose_out8<<<dim3((TFS + 31) / 32, BATCH / 32), dim3(32, 32), 0, stream>>>(out8, out);
}